// Round 9
// baseline (272.232 us; speedup 1.0000x reference)
//
#include <hip/hip_runtime.h>
#include <math.h>

// Problem constants
#define BB 32
#define NREC 64
#define CC 16
#define HW 63

// ---------------- Rectangle render (padded 64x64 plane) ----------------
__global__ __launch_bounds__(256) void render_kernel(const float* __restrict__ x,
                                                     float* __restrict__ layout) {
    int bn = blockIdx.x;                 // b*NREC + n
    const float* xp = x + (size_t)bn * (4 + CC);
    __shared__ int cs[4];
    __shared__ float mps;
    if (threadIdx.x == 0) {
        cs[0] = (int)xp[0]; cs[1] = (int)xp[1];
        cs[2] = (int)xp[2]; cs[3] = (int)xp[3];
        float m = xp[4];
        #pragma unroll
        for (int c = 1; c < CC; ++c) m = fmaxf(m, xp[4 + c]);
        mps = m;
    }
    __syncthreads();
    int xL = cs[0], yT = cs[1], xR = cs[2], yB = cs[3];
    float m = mps;
    float* op = layout + (size_t)bn * 4096;          // 64x64 padded plane
    for (int p = threadIdx.x; p < 4096; p += blockDim.x) {
        int u = p >> 6, v = p & 63;
        bool vb = (u < HW) && (v < HW) &&
                  (((u == xL || u == xR) && (v > yT && v < yB)) ||
                   ((v == yT || v == yB) && (u > xL && u < xR)));
        op[p] = vb ? m : 0.0f;
    }
}

// ---------------- helpers: OX=2 register-direct conv ----------------
template<int HINS>
__device__ __forceinline__ void loadq(float4 (&Q)[3], float (&E)[3],
                                      const float* __restrict__ p) {
    #pragma unroll
    for (int r = 0; r < 3; ++r) {
        Q[r] = *(const float4*)(p + (size_t)r * HINS);   // aligned, coalesced
        E[r] = p[(size_t)r * HINS + 4];
    }
}

template<int CIN, int COG>
__device__ __forceinline__ void fmastage2(const float4 (&Q)[3], const float (&E)[3],
                                          const float* __restrict__ wci,
                                          float (&A0)[COG], float (&A1)[COG]) {
    #pragma unroll
    for (int i = 0; i < COG; ++i) {
        const float* wp = wci + (size_t)i * CIN * 9;     // block-uniform -> s_load
        float a0 = A0[i], a1 = A1[i];
        #pragma unroll
        for (int r = 0; r < 3; ++r) {
            float w0 = wp[r * 3 + 0], w1 = wp[r * 3 + 1], w2 = wp[r * 3 + 2];
            a0 = fmaf(Q[r].x, w0, a0); a0 = fmaf(Q[r].y, w1, a0); a0 = fmaf(Q[r].z, w2, a0);
            a1 = fmaf(Q[r].z, w0, a1); a1 = fmaf(Q[r].w, w1, a1); a1 = fmaf(E[r],  w2, a1);
        }
        A0[i] = a0; A1[i] = a1;
    }
}

// ---------------- Conv 3x3 stride-2 VALID, OX=2, float4, depth-4 ----------
// Input PADDED: row stride HINS (pow2), channel plane PLANE (pow2).
// bid = (cg*TILES+tile)*BB + b -> XCD = b%8 (batch slice L2 locality).
template<int CIN, int COUT, int HINS, int PLANE, int HOUT,
         int CGX, int TH, int NT, int COG>
__global__ __launch_bounds__(NT, 4) void convd_kernel(
        const float* __restrict__ in,    // [B][CIN][*][HINS] activated, padded
        const float* __restrict__ w,     // [COUT][CIN][3][3]
        const float* __restrict__ bias,
        float* __restrict__ out,         // [B][COUT][HOUT][HOUT] raw, packed
        float* __restrict__ psum,        // [COUT][PBLK]
        float* __restrict__ psq) {
    constexpr int TILES = (HOUT + TH - 1) / TH;
    constexpr int PBLK  = BB * TILES;
    constexpr int NW    = NT / 64;

    __shared__ float redbuf[2 * NW * COG];

    int tid = threadIdx.x;
    int bid = blockIdx.x;
    int b    = bid & (BB - 1);
    int t2   = bid / BB;
    int tile = t2 % TILES;
    int cg   = t2 / TILES;
    int co0  = cg * COG;

    int ty = tid / CGX, tx = tid % CGX;
    int oy = tile * TH + ty;
    int ox0 = 2 * tx;
    bool rowok = (ty < TH) && (oy < HOUT);
    bool a0 = rowok && (ox0 < HOUT);
    bool a1 = rowok && (ox0 + 1 < HOUT);
    int oyl = rowok ? oy : 0;
    const float* base = in + (size_t)b * CIN * PLANE + (size_t)(2 * oyl) * HINS + 4 * tx;

    float A0[COG], A1[COG];
    #pragma unroll
    for (int i = 0; i < COG; ++i) { A0[i] = 0.f; A1[i] = 0.f; }

    float4 Qa[3], Qb[3], Qc[3], Qd[3];
    float  Ea[3], Eb[3], Ec[3], Ed[3];
    loadq<HINS>(Qa, Ea, base + 0 * PLANE);
    loadq<HINS>(Qb, Eb, base + 1 * PLANE);
    loadq<HINS>(Qc, Ec, base + 2 * PLANE);
    loadq<HINS>(Qd, Ed, base + 3 * PLANE);

    const float* wb = w + (size_t)co0 * CIN * 9;
    for (int ci = 0; ci < CIN; ci += 4) {
        fmastage2<CIN, COG>(Qa, Ea, wb + (size_t)ci * 9, A0, A1);
        if (ci + 4 < CIN) loadq<HINS>(Qa, Ea, base + (size_t)(ci + 4) * PLANE);
        fmastage2<CIN, COG>(Qb, Eb, wb + (size_t)(ci + 1) * 9, A0, A1);
        if (ci + 5 < CIN) loadq<HINS>(Qb, Eb, base + (size_t)(ci + 5) * PLANE);
        fmastage2<CIN, COG>(Qc, Ec, wb + (size_t)(ci + 2) * 9, A0, A1);
        if (ci + 6 < CIN) loadq<HINS>(Qc, Ec, base + (size_t)(ci + 6) * PLANE);
        fmastage2<CIN, COG>(Qd, Ed, wb + (size_t)(ci + 3) * 9, A0, A1);
        if (ci + 7 < CIN) loadq<HINS>(Qd, Ed, base + (size_t)(ci + 7) * PLANE);
    }

    float* ob = out + ((size_t)b * COUT + co0) * (HOUT * HOUT) + oy * HOUT + ox0;
    #pragma unroll
    for (int i = 0; i < COG; ++i) {
        float v0 = a0 ? (A0[i] + bias[co0 + i]) : 0.f;
        float v1 = a1 ? (A1[i] + bias[co0 + i]) : 0.f;
        if (a0) ob[(size_t)i * (HOUT * HOUT)] = v0;
        if (a1) ob[(size_t)i * (HOUT * HOUT) + 1] = v1;
        A0[i] = v0 + v1;
        A1[i] = v0 * v0 + v1 * v1;
    }

    int lane = tid & 63, wv = tid >> 6;
    #pragma unroll
    for (int i = 0; i < COG; ++i) {
        float s = A0[i], q = A1[i];
        #pragma unroll
        for (int o = 32; o > 0; o >>= 1) {
            s += __shfl_down(s, o, 64);
            q += __shfl_down(q, o, 64);
        }
        if (lane == 0) {
            redbuf[wv * COG + i] = s;
            redbuf[NW * COG + wv * COG + i] = q;
        }
    }
    __syncthreads();
    if (tid < COG) {
        float S_ = 0.f, Q_ = 0.f;
        #pragma unroll
        for (int v2 = 0; v2 < NW; ++v2) {
            S_ += redbuf[v2 * COG + tid];
            Q_ += redbuf[NW * COG + v2 * COG + tid];
        }
        int pb_ = b * TILES + tile;
        psum[(size_t)(co0 + tid) * PBLK + pb_] = S_;
        psq [(size_t)(co0 + tid) * PBLK + pb_] = Q_;
    }
}

// ---------------- conv3: 15->7, padded input (stride 16, plane 256) --------
__global__ __launch_bounds__(256) void conv3_kernel(
        const float* __restrict__ in,    // [B][128][16][16] ACTIVATED padded
        const float* __restrict__ w,     // [128][128][3][3]
        const float* __restrict__ bias,
        float* __restrict__ out,         // [B][128][7][7] raw packed
        float* __restrict__ psum,        // [128][32]
        float* __restrict__ psq) {
    constexpr int COG = 8;
    __shared__ float lin[4 * 8 * 288 + 64];  // 4 waves x 8 ch x (16 rows x 18) + slack
    __shared__ float red[4 * COG * 49];
    __shared__ float fin[COG * 49];

    int tid = threadIdx.x;
    int wv = tid >> 6, lane = tid & 63;
    int wvu = __builtin_amdgcn_readfirstlane(wv);
    int cg = blockIdx.x >> 5;            // cg-major
    int b  = blockIdx.x & 31;
    int co0 = cg * COG;
    int oy = min(lane / 7, 6), ox = lane % 7;
    bool act = lane < 49;

    int loffw[4];
    #pragma unroll
    for (int s = 0; s < 4; ++s) {
        int t = lane + s * 64;           // 0..255, exact
        loffw[s] = (t >> 4) * 18 + (t & 15);
    }

    float acc[COG];
    #pragma unroll
    for (int i = 0; i < COG; ++i) acc[i] = 0.f;

    const float* inw = in + (size_t)b * 128 * 256 + (size_t)wvu * 32 * 256;
    float* ldsw = lin + wvu * (8 * 288);

    float pf[8][4];
    #pragma unroll
    for (int cl = 0; cl < 8; ++cl) {
        #pragma unroll
        for (int s = 0; s < 4; ++s)
            pf[cl][s] = inw[cl * 256 + lane + s * 64];
    }

    for (int kk = 0; kk < 4; ++kk) {
        __syncthreads();
        #pragma unroll
        for (int cl = 0; cl < 8; ++cl) {
            #pragma unroll
            for (int s = 0; s < 4; ++s)
                ldsw[cl * 288 + loffw[s]] = pf[cl][s];
        }
        __syncthreads();
        if (kk < 3) {
            const float* nb = inw + (size_t)(kk + 1) * 8 * 256;
            #pragma unroll
            for (int cl = 0; cl < 8; ++cl) {
                #pragma unroll
                for (int s = 0; s < 4; ++s)
                    pf[cl][s] = nb[cl * 256 + lane + s * 64];
            }
        }
        #pragma unroll
        for (int cl = 0; cl < 8; ++cl) {
            const float* lrow = ldsw + cl * 288 + (2 * oy) * 18 + 2 * ox;
            float p[9];
            #pragma unroll
            for (int ky = 0; ky < 3; ++ky) {
                float2 ab = *(const float2*)(lrow + ky * 18);
                p[ky * 3 + 0] = ab.x;
                p[ky * 3 + 1] = ab.y;
                p[ky * 3 + 2] = lrow[ky * 18 + 2];
            }
            int ci = wvu * 32 + kk * 8 + cl;
            const float* wci = w + ((size_t)co0 * 128 + ci) * 9;
            #pragma unroll
            for (int i = 0; i < COG; ++i) {
                const float* wp = wci + (size_t)i * 128 * 9;
                float a = acc[i];
                a = fmaf(p[0], wp[0], a); a = fmaf(p[1], wp[1], a);
                a = fmaf(p[2], wp[2], a); a = fmaf(p[3], wp[3], a);
                a = fmaf(p[4], wp[4], a); a = fmaf(p[5], wp[5], a);
                a = fmaf(p[6], wp[6], a); a = fmaf(p[7], wp[7], a);
                a = fmaf(p[8], wp[8], a);
                acc[i] = a;
            }
        }
    }

    if (act) {
        #pragma unroll
        for (int i = 0; i < COG; ++i) red[(wv * COG + i) * 49 + lane] = acc[i];
    }
    __syncthreads();

    for (int t = tid; t < COG * 49; t += 256) {
        int i = t / 49, p2 = t % 49;
        float v = red[(0 * COG + i) * 49 + p2] + red[(1 * COG + i) * 49 + p2] +
                  red[(2 * COG + i) * 49 + p2] + red[(3 * COG + i) * 49 + p2];
        v += bias[co0 + i];
        out[((size_t)b * 128 + co0 + i) * 49 + p2] = v;
        fin[t] = v;
    }
    __syncthreads();

    if (tid < COG) {
        float S = 0.f, Q = 0.f;
        for (int p2 = 0; p2 < 49; ++p2) {
            float v = fin[tid * 49 + p2];
            S += v; Q += v * v;
        }
        psum[(size_t)(co0 + tid) * 32 + b] = S;
        psq [(size_t)(co0 + tid) * 32 + b] = Q;
    }
}

// ---------------- Fold partials -> per-channel scale/shift ----------------
__global__ void stats_kernel(const float* __restrict__ psum, const float* __restrict__ psq,
                             const float* __restrict__ g, const float* __restrict__ be,
                             float* __restrict__ scale, float* __restrict__ shift,
                             int COUT, int PBLK, float count) {
    int c = threadIdx.x;
    if (c >= COUT) return;
    float s = 0.f, q = 0.f;
    for (int p = 0; p < PBLK; ++p) {
        s += psum[(size_t)c * PBLK + p];
        q += psq[(size_t)c * PBLK + p];
    }
    float mean = s / count;
    float var  = q / count - mean * mean;
    float sc   = g[c] * rsqrtf(var + 1e-5f);
    scale[c] = sc;
    shift[c] = be[c] - mean * sc;
}

// ---------------- Apply BN+ReLU, packed -> PADDED plane ----------------
// in packed RxC; out plane PL with row stride SR (pow2); pads written as 0.
template<int R, int C, int SR, int PL, int CCH, int NT>
__global__ __launch_bounds__(NT) void apply_pad_kernel(
        const float* __restrict__ raw, const float* __restrict__ scale,
        const float* __restrict__ shift, float* __restrict__ act) {
    int bc = blockIdx.x;
    int c = bc & (CCH - 1);
    const float* rp = raw + (size_t)bc * (R * C);
    float* ap = act + (size_t)bc * PL;
    float s = scale[c], h = shift[c];
    for (int i = threadIdx.x; i < PL; i += NT) {
        int r = i >> 31 ? 0 : i / SR;      // SR is pow2 -> compiler uses shift
        int cc = i & (SR - 1);
        float v = 0.f;
        if (r < R && cc < C) v = fmaxf(fmaf(rp[r * C + cc], s, h), 0.f);
        ap[i] = v;
    }
}

// ---------------- Apply BN+ReLU, packed -> packed (act3) ----------------
__global__ __launch_bounds__(64) void apply_kernel(
        const float* __restrict__ raw, const float* __restrict__ scale,
        const float* __restrict__ shift, float* __restrict__ act,
        int C, int HW2) {
    int bc = blockIdx.x;
    int c = bc % C;
    const float* rp = raw + (size_t)bc * HW2;
    float* ap = act + (size_t)bc * HW2;
    float s = scale[c], h = shift[c];
    for (int i = threadIdx.x; i < HW2; i += 64)
        ap[i] = fmaxf(fmaf(rp[i], s, h), 0.f);
}

// ---------------- FC1: one block per (j, b), float4 ----------------
__global__ __launch_bounds__(256) void fc1_kernel(
        const float* __restrict__ act3,   // [B][6272] activated packed
        const float* __restrict__ fc1w,   // [64][6272]
        const float* __restrict__ fc1b,
        float* __restrict__ h) {          // [B][64]
    const int FLAT4 = 6272 / 4;
    int j = blockIdx.x >> 5;
    int b = blockIdx.x & 31;
    const float4* ip = (const float4*)(act3 + (size_t)b * 6272);
    const float4* wp = (const float4*)(fc1w + (size_t)j * 6272);
    float s = 0.f;
    for (int i = threadIdx.x; i < FLAT4; i += 256) {
        float4 xv = ip[i], wv = wp[i];
        s = fmaf(xv.x, wv.x, s); s = fmaf(xv.y, wv.y, s);
        s = fmaf(xv.z, wv.z, s); s = fmaf(xv.w, wv.w, s);
    }
    #pragma unroll
    for (int o = 32; o > 0; o >>= 1) s += __shfl_down(s, o, 64);
    __shared__ float red[4];
    if ((threadIdx.x & 63) == 0) red[threadIdx.x >> 6] = s;
    __syncthreads();
    if (threadIdx.x == 0) {
        float t = red[0] + red[1] + red[2] + red[3];
        h[b * 64 + j] = fmaxf(t + fc1b[j], 0.f);
    }
}

// ---------------- FC2 + sigmoid ----------------
__global__ __launch_bounds__(64) void fc2_kernel(
        const float* __restrict__ h, const float* __restrict__ fc2w,
        const float* __restrict__ fc2b, float* __restrict__ outp) {
    int b = blockIdx.x;
    float v = h[b * 64 + threadIdx.x] * fc2w[threadIdx.x];
    #pragma unroll
    for (int o = 32; o > 0; o >>= 1) v += __shfl_down(v, o, 64);
    if (threadIdx.x == 0) outp[b] = 1.f / (1.f + expf(-(v + fc2b[0])));
}

// ---------------- Launch ----------------
extern "C" void kernel_launch(void* const* d_in, const int* in_sizes, int n_in,
                              void* d_out, int out_size, void* d_ws, size_t ws_size,
                              hipStream_t stream) {
    const float* x       = (const float*)d_in[0];
    const float* conv1_w = (const float*)d_in[1];
    const float* conv1_b = (const float*)d_in[2];
    const float* bn1_g   = (const float*)d_in[3];
    const float* bn1_b   = (const float*)d_in[4];
    const float* conv2_w = (const float*)d_in[5];
    const float* conv2_b = (const float*)d_in[6];
    const float* bn2_g   = (const float*)d_in[7];
    const float* bn2_b   = (const float*)d_in[8];
    const float* conv3_w = (const float*)d_in[9];
    const float* conv3_b = (const float*)d_in[10];
    const float* bn3_g   = (const float*)d_in[11];
    const float* bn3_b   = (const float*)d_in[12];
    const float* fc1_w   = (const float*)d_in[13];
    const float* fc1_b   = (const float*)d_in[14];
    const float* fc2_w   = (const float*)d_in[15];
    const float* fc2_b   = (const float*)d_in[16];
    float* out = (float*)d_out;

    float* ws = (float*)d_ws;
    size_t off = 0;
    float* layout = ws + off; off += (size_t)BB * NREC * 4096;      // 8,388,608 padded
    float* out1   = ws + off; off += (size_t)BB * 64  * 31 * 31;
    float* out2   = ws + off; off += (size_t)BB * 128 * 15 * 15;
    float* out3   = ws + off; off += (size_t)BB * 128 * 7 * 7;
    float* psum1  = ws + off; off += 64 * 128;
    float* psq1   = ws + off; off += 64 * 128;
    float* psum2  = ws + off; off += 128 * 32;
    float* psq2   = ws + off; off += 128 * 32;
    float* psum3  = ws + off; off += 128 * 32;
    float* psq3   = ws + off; off += 128 * 32;
    float* scale1 = ws + off; off += 64;
    float* shift1 = ws + off; off += 64;
    float* scale2 = ws + off; off += 128;
    float* shift2 = ws + off; off += 128;
    float* scale3 = ws + off; off += 128;
    float* shift3 = ws + off; off += 128;
    float* hbuf   = ws + off; off += BB * 64;
    // padded activated buffers alias the layout region (dead after conv1)
    float* act1 = layout;                     // 32*64*1024  = 2,097,152
    float* act2 = layout + 2097152;           // 32*128*256  = 1,048,576
    float* act3 = layout + 3145728;           // 32*128*49   =   200,704 (packed)

    render_kernel<<<BB * NREC, 256, 0, stream>>>(x, layout);

    // conv1: 63->31, padded stride 64/plane 4096, OX=2, COG=8, TH=8 (4 tiles)
    // grid = 8cg * 4tiles * 32b = 1024 blocks x 128 thr
    convd_kernel<64, 64, 64, 4096, 31, 16, 8, 128, 8>
        <<<8 * 4 * 32, 128, 0, stream>>>(layout, conv1_w, conv1_b,
                                         out1, psum1, psq1);
    stats_kernel<<<1, 64, 0, stream>>>(psum1, psq1, bn1_g, bn1_b, scale1, shift1,
                                       64, 32 * 4, (float)(BB * 31 * 31));
    apply_pad_kernel<31, 31, 32, 1024, 64, 256>
        <<<BB * 64, 256, 0, stream>>>(out1, scale1, shift1, act1);

    // conv2: 31->15, padded stride 32/plane 1024, OX=2, COG=4, TH=15 (1 tile)
    // grid = 32cg * 32b = 1024 blocks x 128 thr
    convd_kernel<64, 128, 32, 1024, 15, 8, 15, 128, 4>
        <<<32 * 32, 128, 0, stream>>>(act1, conv2_w, conv2_b,
                                      out2, psum2, psq2);
    stats_kernel<<<1, 128, 0, stream>>>(psum2, psq2, bn2_g, bn2_b, scale2, shift2,
                                        128, 32, (float)(BB * 15 * 15));
    apply_pad_kernel<15, 15, 16, 256, 128, 256>
        <<<BB * 128, 256, 0, stream>>>(out2, scale2, shift2, act2);

    // conv3: 15->7 (padded input), wave-split CIN, COG=8 -> grid 16*32 = 512
    conv3_kernel<<<16 * 32, 256, 0, stream>>>(act2, conv3_w, conv3_b,
                                              out3, psum3, psq3);
    stats_kernel<<<1, 128, 0, stream>>>(psum3, psq3, bn3_g, bn3_b, scale3, shift3,
                                        128, 32, (float)(BB * 7 * 7));
    apply_kernel<<<BB * 128, 64, 0, stream>>>(out3, scale3, shift3, act3, 128, 49);

    fc1_kernel<<<64 * 32, 256, 0, stream>>>(act3, fc1_w, fc1_b, hbuf);
    fc2_kernel<<<BB, 64, 0, stream>>>(hbuf, fc2_w, fc2_b, out);
}

// Round 10
// 260.167 us; speedup vs baseline: 1.0464x; 1.0464x over previous
//
#include <hip/hip_runtime.h>
#include <math.h>

// Problem constants
#define BB 32
#define NREC 64
#define CC 16
#define HW 63

// ---------------- Rectangle render (padded 64x64 plane) ----------------
__global__ __launch_bounds__(256) void render_kernel(const float* __restrict__ x,
                                                     float* __restrict__ layout) {
    int bn = blockIdx.x;                 // b*NREC + n
    const float* xp = x + (size_t)bn * (4 + CC);
    __shared__ int cs[4];
    __shared__ float mps;
    if (threadIdx.x == 0) {
        cs[0] = (int)xp[0]; cs[1] = (int)xp[1];
        cs[2] = (int)xp[2]; cs[3] = (int)xp[3];
        float m = xp[4];
        #pragma unroll
        for (int c = 1; c < CC; ++c) m = fmaxf(m, xp[4 + c]);
        mps = m;
    }
    __syncthreads();
    int xL = cs[0], yT = cs[1], xR = cs[2], yB = cs[3];
    float m = mps;
    float* op = layout + (size_t)bn * 4096;          // 64x64 padded plane
    for (int p = threadIdx.x; p < 4096; p += blockDim.x) {
        int u = p >> 6, v = p & 63;
        bool vb = (u < HW) && (v < HW) &&
                  (((u == xL || u == xR) && (v > yT && v < yB)) ||
                   ((v == yT || v == yB) && (u > xL && u < xR)));
        op[p] = vb ? m : 0.0f;
    }
}

// ---------------- helpers: OX=2 register-direct conv ----------------
template<int HINS>
__device__ __forceinline__ void loadq(float4 (&Q)[3], float (&E)[3],
                                      const float* __restrict__ p) {
    #pragma unroll
    for (int r = 0; r < 3; ++r) {
        Q[r] = *(const float4*)(p + (size_t)r * HINS);   // aligned, coalesced
        E[r] = p[(size_t)r * HINS + 4];
    }
}

template<int CIN, int COG>
__device__ __forceinline__ void fmastage2(const float4 (&Q)[3], const float (&E)[3],
                                          const float* __restrict__ wci,
                                          float (&A0)[COG], float (&A1)[COG]) {
    #pragma unroll
    for (int i = 0; i < COG; ++i) {
        const float* wp = wci + (size_t)i * CIN * 9;     // block-uniform -> s_load
        float a0 = A0[i], a1 = A1[i];
        #pragma unroll
        for (int r = 0; r < 3; ++r) {
            float w0 = wp[r * 3 + 0], w1 = wp[r * 3 + 1], w2 = wp[r * 3 + 2];
            a0 = fmaf(Q[r].x, w0, a0); a0 = fmaf(Q[r].y, w1, a0); a0 = fmaf(Q[r].z, w2, a0);
            a1 = fmaf(Q[r].z, w0, a1); a1 = fmaf(Q[r].w, w1, a1); a1 = fmaf(E[r],  w2, a1);
        }
        A0[i] = a0; A1[i] = a1;
    }
}

// ---------------- Conv 3x3 stride-2 VALID, OX=2, float4, depth-4 ----------
// Input PADDED: row stride HINS (pow2), channel plane PLANE (pow2).
// bid = (cg*TILES+tile)*BB + b -> XCD = b%8 (batch slice L2 locality).
// ci loop kept rolled (#pragma unroll 1): 4-stage body stays I-cache resident
// and the scheduler can pipeline the next stage's 36-SGPR weight s_loads.
template<int CIN, int COUT, int HINS, int PLANE, int HOUT,
         int CGX, int TH, int NT, int COG>
__global__ __launch_bounds__(NT, 4) void convd_kernel(
        const float* __restrict__ in,    // [B][CIN][*][HINS] activated, padded
        const float* __restrict__ w,     // [COUT][CIN][3][3]
        const float* __restrict__ bias,
        float* __restrict__ out,         // [B][COUT][HOUT][HOUT] raw, packed
        float* __restrict__ psum,        // [COUT][PBLK]
        float* __restrict__ psq) {
    constexpr int TILES = (HOUT + TH - 1) / TH;
    constexpr int PBLK  = BB * TILES;
    constexpr int NW    = NT / 64;

    __shared__ float redbuf[2 * NW * COG];

    int tid = threadIdx.x;
    int bid = blockIdx.x;
    int b    = bid & (BB - 1);
    int t2   = bid / BB;
    int tile = t2 % TILES;
    int cg   = t2 / TILES;
    int co0  = cg * COG;

    int ty = tid / CGX, tx = tid % CGX;
    int oy = tile * TH + ty;
    int ox0 = 2 * tx;
    bool rowok = (ty < TH) && (oy < HOUT);
    bool a0 = rowok && (ox0 < HOUT);
    bool a1 = rowok && (ox0 + 1 < HOUT);
    int oyl = rowok ? oy : 0;
    const float* base = in + (size_t)b * CIN * PLANE + (size_t)(2 * oyl) * HINS + 4 * tx;

    float A0[COG], A1[COG];
    #pragma unroll
    for (int i = 0; i < COG; ++i) { A0[i] = 0.f; A1[i] = 0.f; }

    float4 Qa[3], Qb[3], Qc[3], Qd[3];
    float  Ea[3], Eb[3], Ec[3], Ed[3];
    loadq<HINS>(Qa, Ea, base + 0 * PLANE);
    loadq<HINS>(Qb, Eb, base + 1 * PLANE);
    loadq<HINS>(Qc, Ec, base + 2 * PLANE);
    loadq<HINS>(Qd, Ed, base + 3 * PLANE);

    const float* wb = w + (size_t)co0 * CIN * 9;
    #pragma unroll 1
    for (int ci = 0; ci < CIN; ci += 4) {
        fmastage2<CIN, COG>(Qa, Ea, wb + (size_t)ci * 9, A0, A1);
        if (ci + 4 < CIN) loadq<HINS>(Qa, Ea, base + (size_t)(ci + 4) * PLANE);
        fmastage2<CIN, COG>(Qb, Eb, wb + (size_t)(ci + 1) * 9, A0, A1);
        if (ci + 5 < CIN) loadq<HINS>(Qb, Eb, base + (size_t)(ci + 5) * PLANE);
        fmastage2<CIN, COG>(Qc, Ec, wb + (size_t)(ci + 2) * 9, A0, A1);
        if (ci + 6 < CIN) loadq<HINS>(Qc, Ec, base + (size_t)(ci + 6) * PLANE);
        fmastage2<CIN, COG>(Qd, Ed, wb + (size_t)(ci + 3) * 9, A0, A1);
        if (ci + 7 < CIN) loadq<HINS>(Qd, Ed, base + (size_t)(ci + 7) * PLANE);
    }

    float* ob = out + ((size_t)b * COUT + co0) * (HOUT * HOUT) + oy * HOUT + ox0;
    #pragma unroll
    for (int i = 0; i < COG; ++i) {
        float v0 = a0 ? (A0[i] + bias[co0 + i]) : 0.f;
        float v1 = a1 ? (A1[i] + bias[co0 + i]) : 0.f;
        if (a0) ob[(size_t)i * (HOUT * HOUT)] = v0;
        if (a1) ob[(size_t)i * (HOUT * HOUT) + 1] = v1;
        A0[i] = v0 + v1;
        A1[i] = v0 * v0 + v1 * v1;
    }

    int lane = tid & 63, wv = tid >> 6;
    #pragma unroll
    for (int i = 0; i < COG; ++i) {
        float s = A0[i], q = A1[i];
        #pragma unroll
        for (int o = 32; o > 0; o >>= 1) {
            s += __shfl_down(s, o, 64);
            q += __shfl_down(q, o, 64);
        }
        if (lane == 0) {
            redbuf[wv * COG + i] = s;
            redbuf[NW * COG + wv * COG + i] = q;
        }
    }
    __syncthreads();
    if (tid < COG) {
        float S_ = 0.f, Q_ = 0.f;
        #pragma unroll
        for (int v2 = 0; v2 < NW; ++v2) {
            S_ += redbuf[v2 * COG + tid];
            Q_ += redbuf[NW * COG + v2 * COG + tid];
        }
        int pb_ = b * TILES + tile;
        psum[(size_t)(co0 + tid) * PBLK + pb_] = S_;
        psq [(size_t)(co0 + tid) * PBLK + pb_] = Q_;
    }
}

// ---------------- conv3: 15->7, padded input (stride 16, plane 256) --------
__global__ __launch_bounds__(256) void conv3_kernel(
        const float* __restrict__ in,    // [B][128][16][16] ACTIVATED padded
        const float* __restrict__ w,     // [128][128][3][3]
        const float* __restrict__ bias,
        float* __restrict__ out,         // [B][128][7][7] raw packed
        float* __restrict__ psum,        // [128][32]
        float* __restrict__ psq) {
    constexpr int COG = 8;
    __shared__ float lin[4 * 8 * 288 + 64];  // 4 waves x 8 ch x (16 rows x 18) + slack
    __shared__ float red[4 * COG * 49];
    __shared__ float fin[COG * 49];

    int tid = threadIdx.x;
    int wv = tid >> 6, lane = tid & 63;
    int wvu = __builtin_amdgcn_readfirstlane(wv);
    int cg = blockIdx.x >> 5;            // cg-major
    int b  = blockIdx.x & 31;
    int co0 = cg * COG;
    int oy = min(lane / 7, 6), ox = lane % 7;
    bool act = lane < 49;

    int loffw[4];
    #pragma unroll
    for (int s = 0; s < 4; ++s) {
        int t = lane + s * 64;           // 0..255, exact
        loffw[s] = (t >> 4) * 18 + (t & 15);
    }

    float acc[COG];
    #pragma unroll
    for (int i = 0; i < COG; ++i) acc[i] = 0.f;

    const float* inw = in + (size_t)b * 128 * 256 + (size_t)wvu * 32 * 256;
    float* ldsw = lin + wvu * (8 * 288);

    float pf[8][4];
    #pragma unroll
    for (int cl = 0; cl < 8; ++cl) {
        #pragma unroll
        for (int s = 0; s < 4; ++s)
            pf[cl][s] = inw[cl * 256 + lane + s * 64];
    }

    #pragma unroll 1
    for (int kk = 0; kk < 4; ++kk) {
        __syncthreads();
        #pragma unroll
        for (int cl = 0; cl < 8; ++cl) {
            #pragma unroll
            for (int s = 0; s < 4; ++s)
                ldsw[cl * 288 + loffw[s]] = pf[cl][s];
        }
        __syncthreads();
        if (kk < 3) {
            const float* nb = inw + (size_t)(kk + 1) * 8 * 256;
            #pragma unroll
            for (int cl = 0; cl < 8; ++cl) {
                #pragma unroll
                for (int s = 0; s < 4; ++s)
                    pf[cl][s] = nb[cl * 256 + lane + s * 64];
            }
        }
        #pragma unroll
        for (int cl = 0; cl < 8; ++cl) {
            const float* lrow = ldsw + cl * 288 + (2 * oy) * 18 + 2 * ox;
            float p[9];
            #pragma unroll
            for (int ky = 0; ky < 3; ++ky) {
                float2 ab = *(const float2*)(lrow + ky * 18);
                p[ky * 3 + 0] = ab.x;
                p[ky * 3 + 1] = ab.y;
                p[ky * 3 + 2] = lrow[ky * 18 + 2];
            }
            int ci = wvu * 32 + kk * 8 + cl;
            const float* wci = w + ((size_t)co0 * 128 + ci) * 9;
            #pragma unroll
            for (int i = 0; i < COG; ++i) {
                const float* wp = wci + (size_t)i * 128 * 9;
                float a = acc[i];
                a = fmaf(p[0], wp[0], a); a = fmaf(p[1], wp[1], a);
                a = fmaf(p[2], wp[2], a); a = fmaf(p[3], wp[3], a);
                a = fmaf(p[4], wp[4], a); a = fmaf(p[5], wp[5], a);
                a = fmaf(p[6], wp[6], a); a = fmaf(p[7], wp[7], a);
                a = fmaf(p[8], wp[8], a);
                acc[i] = a;
            }
        }
    }

    if (act) {
        #pragma unroll
        for (int i = 0; i < COG; ++i) red[(wv * COG + i) * 49 + lane] = acc[i];
    }
    __syncthreads();

    for (int t = tid; t < COG * 49; t += 256) {
        int i = t / 49, p2 = t % 49;
        float v = red[(0 * COG + i) * 49 + p2] + red[(1 * COG + i) * 49 + p2] +
                  red[(2 * COG + i) * 49 + p2] + red[(3 * COG + i) * 49 + p2];
        v += bias[co0 + i];
        out[((size_t)b * 128 + co0 + i) * 49 + p2] = v;
        fin[t] = v;
    }
    __syncthreads();

    if (tid < COG) {
        float S = 0.f, Q = 0.f;
        for (int p2 = 0; p2 < 49; ++p2) {
            float v = fin[tid * 49 + p2];
            S += v; Q += v * v;
        }
        psum[(size_t)(co0 + tid) * 32 + b] = S;
        psq [(size_t)(co0 + tid) * 32 + b] = Q;
    }
}

// ---------------- Fold partials -> per-channel scale/shift ----------------
__global__ void stats_kernel(const float* __restrict__ psum, const float* __restrict__ psq,
                             const float* __restrict__ g, const float* __restrict__ be,
                             float* __restrict__ scale, float* __restrict__ shift,
                             int COUT, int PBLK, float count) {
    int c = threadIdx.x;
    if (c >= COUT) return;
    float s = 0.f, q = 0.f;
    for (int p = 0; p < PBLK; ++p) {
        s += psum[(size_t)c * PBLK + p];
        q += psq[(size_t)c * PBLK + p];
    }
    float mean = s / count;
    float var  = q / count - mean * mean;
    float sc   = g[c] * rsqrtf(var + 1e-5f);
    scale[c] = sc;
    shift[c] = be[c] - mean * sc;
}

// ---------------- Apply BN+ReLU, packed -> PADDED plane ----------------
template<int R, int C, int SR, int PL, int CCH, int NT>
__global__ __launch_bounds__(NT) void apply_pad_kernel(
        const float* __restrict__ raw, const float* __restrict__ scale,
        const float* __restrict__ shift, float* __restrict__ act) {
    int bc = blockIdx.x;
    int c = bc & (CCH - 1);
    const float* rp = raw + (size_t)bc * (R * C);
    float* ap = act + (size_t)bc * PL;
    float s = scale[c], h = shift[c];
    for (int i = threadIdx.x; i < PL; i += NT) {
        int r = i / SR;                    // SR pow2 -> shift
        int cc = i & (SR - 1);
        float v = 0.f;
        if (r < R && cc < C) v = fmaxf(fmaf(rp[r * C + cc], s, h), 0.f);
        ap[i] = v;
    }
}

// ---------------- Apply BN+ReLU, packed -> packed (act3) ----------------
__global__ __launch_bounds__(64) void apply_kernel(
        const float* __restrict__ raw, const float* __restrict__ scale,
        const float* __restrict__ shift, float* __restrict__ act,
        int C, int HW2) {
    int bc = blockIdx.x;
    int c = bc % C;
    const float* rp = raw + (size_t)bc * HW2;
    float* ap = act + (size_t)bc * HW2;
    float s = scale[c], h = shift[c];
    for (int i = threadIdx.x; i < HW2; i += 64)
        ap[i] = fmaxf(fmaf(rp[i], s, h), 0.f);
}

// ---------------- FC1: one block per (j, b), float4 ----------------
__global__ __launch_bounds__(256) void fc1_kernel(
        const float* __restrict__ act3,   // [B][6272] activated packed
        const float* __restrict__ fc1w,   // [64][6272]
        const float* __restrict__ fc1b,
        float* __restrict__ h) {          // [B][64]
    const int FLAT4 = 6272 / 4;
    int j = blockIdx.x >> 5;
    int b = blockIdx.x & 31;
    const float4* ip = (const float4*)(act3 + (size_t)b * 6272);
    const float4* wp = (const float4*)(fc1w + (size_t)j * 6272);
    float s = 0.f;
    for (int i = threadIdx.x; i < FLAT4; i += 256) {
        float4 xv = ip[i], wv = wp[i];
        s = fmaf(xv.x, wv.x, s); s = fmaf(xv.y, wv.y, s);
        s = fmaf(xv.z, wv.z, s); s = fmaf(xv.w, wv.w, s);
    }
    #pragma unroll
    for (int o = 32; o > 0; o >>= 1) s += __shfl_down(s, o, 64);
    __shared__ float red[4];
    if ((threadIdx.x & 63) == 0) red[threadIdx.x >> 6] = s;
    __syncthreads();
    if (threadIdx.x == 0) {
        float t = red[0] + red[1] + red[2] + red[3];
        h[b * 64 + j] = fmaxf(t + fc1b[j], 0.f);
    }
}

// ---------------- FC2 + sigmoid ----------------
__global__ __launch_bounds__(64) void fc2_kernel(
        const float* __restrict__ h, const float* __restrict__ fc2w,
        const float* __restrict__ fc2b, float* __restrict__ outp) {
    int b = blockIdx.x;
    float v = h[b * 64 + threadIdx.x] * fc2w[threadIdx.x];
    #pragma unroll
    for (int o = 32; o > 0; o >>= 1) v += __shfl_down(v, o, 64);
    if (threadIdx.x == 0) outp[b] = 1.f / (1.f + expf(-(v + fc2b[0])));
}

// ---------------- Launch ----------------
extern "C" void kernel_launch(void* const* d_in, const int* in_sizes, int n_in,
                              void* d_out, int out_size, void* d_ws, size_t ws_size,
                              hipStream_t stream) {
    const float* x       = (const float*)d_in[0];
    const float* conv1_w = (const float*)d_in[1];
    const float* conv1_b = (const float*)d_in[2];
    const float* bn1_g   = (const float*)d_in[3];
    const float* bn1_b   = (const float*)d_in[4];
    const float* conv2_w = (const float*)d_in[5];
    const float* conv2_b = (const float*)d_in[6];
    const float* bn2_g   = (const float*)d_in[7];
    const float* bn2_b   = (const float*)d_in[8];
    const float* conv3_w = (const float*)d_in[9];
    const float* conv3_b = (const float*)d_in[10];
    const float* bn3_g   = (const float*)d_in[11];
    const float* bn3_b   = (const float*)d_in[12];
    const float* fc1_w   = (const float*)d_in[13];
    const float* fc1_b   = (const float*)d_in[14];
    const float* fc2_w   = (const float*)d_in[15];
    const float* fc2_b   = (const float*)d_in[16];
    float* out = (float*)d_out;

    float* ws = (float*)d_ws;
    size_t off = 0;
    float* layout = ws + off; off += (size_t)BB * NREC * 4096;      // padded
    float* out1   = ws + off; off += (size_t)BB * 64  * 31 * 31;
    float* out2   = ws + off; off += (size_t)BB * 128 * 15 * 15;
    float* out3   = ws + off; off += (size_t)BB * 128 * 7 * 7;
    float* psum1  = ws + off; off += 64 * 128;
    float* psq1   = ws + off; off += 64 * 128;
    float* psum2  = ws + off; off += 128 * 32;
    float* psq2   = ws + off; off += 128 * 32;
    float* psum3  = ws + off; off += 128 * 32;
    float* psq3   = ws + off; off += 128 * 32;
    float* scale1 = ws + off; off += 64;
    float* shift1 = ws + off; off += 64;
    float* scale2 = ws + off; off += 128;
    float* shift2 = ws + off; off += 128;
    float* scale3 = ws + off; off += 128;
    float* shift3 = ws + off; off += 128;
    float* hbuf   = ws + off; off += BB * 64;
    // padded activated buffers alias the layout region (dead after conv1)
    float* act1 = layout;                     // 32*64*1024  = 2,097,152
    float* act2 = layout + 2097152;           // 32*128*256  = 1,048,576
    float* act3 = layout + 3145728;           // 32*128*49   =   200,704 (packed)

    render_kernel<<<BB * NREC, 256, 0, stream>>>(x, layout);

    // conv1: 63->31, stride 64/plane 4096, OX=2, COG=4, NT=256, TH=16 (2 tiles)
    // grid = 16cg * 2tiles * 32b = 1024 blocks x 4 waves = 16 waves/CU
    convd_kernel<64, 64, 64, 4096, 31, 16, 16, 256, 4>
        <<<16 * 2 * 32, 256, 0, stream>>>(layout, conv1_w, conv1_b,
                                          out1, psum1, psq1);
    stats_kernel<<<1, 64, 0, stream>>>(psum1, psq1, bn1_g, bn1_b, scale1, shift1,
                                       64, 32 * 2, (float)(BB * 31 * 31));
    apply_pad_kernel<31, 31, 32, 1024, 64, 256>
        <<<BB * 64, 256, 0, stream>>>(out1, scale1, shift1, act1);

    // conv2: 31->15, stride 32/plane 1024, OX=2, COG=2, NT=128, TH=16 (1 tile)
    // grid = 64cg * 32b = 2048 blocks x 2 waves = 16 waves/CU
    convd_kernel<64, 128, 32, 1024, 15, 8, 16, 128, 2>
        <<<64 * 32, 128, 0, stream>>>(act1, conv2_w, conv2_b,
                                      out2, psum2, psq2);
    stats_kernel<<<1, 128, 0, stream>>>(psum2, psq2, bn2_g, bn2_b, scale2, shift2,
                                        128, 32, (float)(BB * 15 * 15));
    apply_pad_kernel<15, 15, 16, 256, 128, 256>
        <<<BB * 128, 256, 0, stream>>>(out2, scale2, shift2, act2);

    // conv3: 15->7 (padded input), wave-split CIN, COG=8 -> grid 16*32 = 512
    conv3_kernel<<<16 * 32, 256, 0, stream>>>(act2, conv3_w, conv3_b,
                                              out3, psum3, psq3);
    stats_kernel<<<1, 128, 0, stream>>>(psum3, psq3, bn3_g, bn3_b, scale3, shift3,
                                        128, 32, (float)(BB * 7 * 7));
    apply_kernel<<<BB * 128, 64, 0, stream>>>(out3, scale3, shift3, act3, 128, 49);

    fc1_kernel<<<64 * 32, 256, 0, stream>>>(act3, fc1_w, fc1_b, hbuf);
    fc2_kernel<<<BB, 64, 0, stream>>>(hbuf, fc2_w, fc2_b, out);
}

// Round 11
// 155.395 us; speedup vs baseline: 1.7519x; 1.6742x over previous
//
#include <hip/hip_runtime.h>
#include <math.h>

#define BB 32
#define NREC 64
#define CC 16
#define HW 63

typedef __attribute__((ext_vector_type(8))) short bf16x8;
typedef __attribute__((ext_vector_type(4))) short bf16x4;
typedef __attribute__((ext_vector_type(4))) float f32x4;

__device__ __forceinline__ unsigned short f2b(float x) {
    unsigned u = __float_as_uint(x);
    u += 0x7fffu + ((u >> 16) & 1u);     // RNE; inputs finite
    return (unsigned short)(u >> 16);
}

// ---------------- Rectangle render -> NHWC bf16 [b][64u][64v][64n] ----------
__global__ __launch_bounds__(64) void render_nhwc_kernel(const float* __restrict__ x,
                                                         unsigned short* __restrict__ lay) {
    int b = blockIdx.x >> 6;
    int u = blockIdx.x & 63;
    int n = threadIdx.x;
    const float* xp = x + ((size_t)b * 64 + n) * 20;
    int xL = (int)xp[0], yT = (int)xp[1], xR = (int)xp[2], yB = (int)xp[3];
    float m = xp[4];
    #pragma unroll
    for (int c = 1; c < CC; ++c) m = fmaxf(m, xp[4 + c]);
    unsigned short mu = f2b(m);
    unsigned short* op = lay + (((size_t)b * 64 + u) * 64) * 64 + n;
    for (int v = 0; v < 64; ++v) {
        bool vb = (u < HW) && (v < HW) &&
                  (((u == xL || u == xR) && (v > yT && v < yB)) ||
                   ((v == yT || v == yB) && (u > xL && u < xR)));
        op[(size_t)v * 64] = vb ? mu : (unsigned short)0;
    }
}

// ---------------- Weight prepack: [CO][CI][3][3] f32 -> [CO][K] bf16 --------
// k = r*CIN + ci, r = ky*3+kx
__global__ __launch_bounds__(256) void wpack_kernel(const float* __restrict__ w,
                                                    unsigned short* __restrict__ wp,
                                                    int COUT, int CIN) {
    int K = CIN * 9;
    int idx = blockIdx.x * 256 + threadIdx.x;
    if (idx >= COUT * K) return;
    int co = idx / K, k = idx - co * K;
    int r = k / CIN, ci = k - r * CIN;
    wp[idx] = f2b(w[((size_t)co * CIN + ci) * 9 + r]);
}

// ---------------- MFMA implicit-GEMM conv 3x3 stride-2 VALID ----------------
// src NHWC bf16 [B][SR][SC][CIN]; wp [COUT][K] bf16; out f32 [B][COUT][HOUT^2].
// Block: (b minor for XCD-L2, rg, mg). 256 thr = 4 waves; wave = 1 mtile.
// Stage LDS [STR][STC][CIP=36] bf16 per 32-ci block; 9 r-ksteps per stage.
template<int CIN, int COUT, int SR, int SC, int HOUT, int OCP, int RG, int RGP, int MGN>
__global__ __launch_bounds__(256) void gemmconv_kernel(
        const unsigned short* __restrict__ src,
        const unsigned short* __restrict__ wp,
        const float* __restrict__ bias,
        float* __restrict__ out) {
    constexpr int K   = 9 * CIN;
    constexpr int NTB = RGP * OCP / 16;
    constexpr int STR = 2 * RGP + 1;
    constexpr int STC = 2 * OCP + 1;
    constexpr int CIP = 36;
    constexpr int MTB = COUT / 16 / MGN;
    constexpr int NRG = (HOUT + RG - 1) / RG;

    __shared__ unsigned short stage[STR * STC * CIP];

    int tid = threadIdx.x;
    int wv = tid >> 6, lane = tid & 63;
    int l15 = lane & 15, lg = lane >> 4;
    int bid = blockIdx.x;
    int b  = bid & 31;
    int t2 = bid >> 5;
    int rg = t2 % NRG;
    int mg = t2 / NRG;
    int co0 = mg * (COUT / MGN);
    int mw = wv % MTB;

    f32x4 acc[NTB];
    #pragma unroll
    for (int i = 0; i < NTB; ++i) acc[i] = (f32x4){0.f, 0.f, 0.f, 0.f};

    const unsigned short* srcb = src + (size_t)b * SR * SC * CIN;
    int srow0 = 2 * rg * RG;

    for (int cb = 0; cb < CIN / 32; ++cb) {
        __syncthreads();
        // stage fill: 32 ci (16 u32) per (row,col)
        for (int idx = tid; idx < STR * STC * 16; idx += 256) {
            int ci2 = idx & 15;
            int rc  = idx >> 4;
            int row = rc / STC, col = rc - row * STC;
            int srow = srow0 + row;
            unsigned v = 0;
            if (srow < SR && col < SC)
                v = *(const unsigned*)(srcb + ((size_t)srow * SC + col) * CIN + cb * 32 + ci2 * 2);
            *(unsigned*)(stage + (row * STC + col) * CIP + ci2 * 2) = v;
        }
        __syncthreads();
        #pragma unroll
        for (int r = 0; r < 9; ++r) {
            int ky = r / 3, kx = r % 3;
            int kk = r * CIN + cb * 32 + lg * 8;
            bf16x8 af = *(const bf16x8*)(wp + (size_t)(co0 + mw * 16 + l15) * K + kk);
            #pragma unroll
            for (int nt = 0; nt < NTB; ++nt) {
                int n = nt * 16 + l15;
                int dy = n / OCP, oxx = n % OCP;              // OCP pow2
                const unsigned short* sp =
                    stage + ((2 * dy + ky) * STC + (2 * oxx + kx)) * CIP + lg * 8;
                bf16x4 blo = *(const bf16x4*)sp;
                bf16x4 bhi = *(const bf16x4*)(sp + 4);
                bf16x8 bfr;
                bfr[0] = blo[0]; bfr[1] = blo[1]; bfr[2] = blo[2]; bfr[3] = blo[3];
                bfr[4] = bhi[0]; bfr[5] = bhi[1]; bfr[6] = bhi[2]; bfr[7] = bhi[3];
                acc[nt] = __builtin_amdgcn_mfma_f32_16x16x32_bf16(af, bfr, acc[nt], 0, 0, 0);
            }
        }
    }

    // epilogue: D col = lane&15 (n), row = lg*4+q (m)
    #pragma unroll
    for (int nt = 0; nt < NTB; ++nt) {
        int n = nt * 16 + l15;
        int oy = rg * RG + n / OCP, oxx = n % OCP;
        if (oy < HOUT && oxx < HOUT) {
            #pragma unroll
            for (int q = 0; q < 4; ++q) {
                int co = co0 + mw * 16 + lg * 4 + q;
                out[((size_t)b * COUT + co) * (HOUT * HOUT) + oy * HOUT + oxx] =
                    acc[nt][q] + bias[co];
            }
        }
    }
}

// ---------------- BN stats from raw conv output ----------------
__global__ __launch_bounds__(256) void stats_raw_kernel(
        const float* __restrict__ raw, const float* __restrict__ g,
        const float* __restrict__ be, float* __restrict__ scale,
        float* __restrict__ shift, int C, int HW2, float count) {
    int c = blockIdx.x;
    float s = 0.f, q = 0.f;
    int total = BB * HW2;
    for (int i = threadIdx.x; i < total; i += 256) {
        int bb = i / HW2, p = i - bb * HW2;
        float x = raw[((size_t)bb * C + c) * HW2 + p];
        s += x; q += x * x;
    }
    __shared__ float rs[4], rq[4];
    int lane = threadIdx.x & 63, wv = threadIdx.x >> 6;
    #pragma unroll
    for (int o = 32; o > 0; o >>= 1) { s += __shfl_down(s, o, 64); q += __shfl_down(q, o, 64); }
    if (lane == 0) { rs[wv] = s; rq[wv] = q; }
    __syncthreads();
    if (threadIdx.x == 0) {
        float S = rs[0] + rs[1] + rs[2] + rs[3];
        float Q = rq[0] + rq[1] + rq[2] + rq[3];
        float mean = S / count;
        float var  = Q / count - mean * mean;
        float sc   = g[c] * rsqrtf(var + 1e-5f);
        scale[c] = sc;
        shift[c] = be[c] - mean * sc;
    }
}

// ---------------- BN+ReLU + transpose to NHWC bf16 (col-padded) -------------
// raw [b][C][R*R] f32 -> act [b][R][SCo][C] bf16, cols >= R zeroed
template<int C, int R, int SCo>
__global__ __launch_bounds__(256) void applyT_kernel(
        const float* __restrict__ raw, const float* __restrict__ scale,
        const float* __restrict__ shift, unsigned short* __restrict__ act) {
    int b = blockIdx.x / R, row = blockIdx.x % R;
    __shared__ float lds[C * (R + 2)];
    for (int idx = threadIdx.x; idx < C * R; idx += 256) {
        int ci = idx / R, col = idx - ci * R;
        float v = fmaxf(fmaf(raw[((size_t)b * C + ci) * (R * R) + row * R + col],
                             scale[ci], shift[ci]), 0.f);
        lds[ci * (R + 2) + col] = v;
    }
    __syncthreads();
    for (int idx = threadIdx.x; idx < SCo * C; idx += 256) {
        int col = idx / C, ci = idx - col * C;
        unsigned short v = 0;
        if (col < R) v = f2b(lds[ci * (R + 2) + col]);
        act[(((size_t)b * R + row) * SCo + col) * C + ci] = v;
    }
}

// ---------------- BN+ReLU packed f32 (act3 for FC) ----------------
__global__ __launch_bounds__(64) void apply_kernel(
        const float* __restrict__ raw, const float* __restrict__ scale,
        const float* __restrict__ shift, float* __restrict__ act,
        int C, int HW2) {
    int bc = blockIdx.x;
    int c = bc % C;
    const float* rp = raw + (size_t)bc * HW2;
    float* ap = act + (size_t)bc * HW2;
    float s = scale[c], h = shift[c];
    for (int i = threadIdx.x; i < HW2; i += 64)
        ap[i] = fmaxf(fmaf(rp[i], s, h), 0.f);
}

// ---------------- FC1: one block per (j, b), float4 ----------------
__global__ __launch_bounds__(256) void fc1_kernel(
        const float* __restrict__ act3, const float* __restrict__ fc1w,
        const float* __restrict__ fc1b, float* __restrict__ h) {
    const int FLAT4 = 6272 / 4;
    int j = blockIdx.x >> 5;
    int b = blockIdx.x & 31;
    const float4* ip = (const float4*)(act3 + (size_t)b * 6272);
    const float4* wp = (const float4*)(fc1w + (size_t)j * 6272);
    float s = 0.f;
    for (int i = threadIdx.x; i < FLAT4; i += 256) {
        float4 xv = ip[i], wv = wp[i];
        s = fmaf(xv.x, wv.x, s); s = fmaf(xv.y, wv.y, s);
        s = fmaf(xv.z, wv.z, s); s = fmaf(xv.w, wv.w, s);
    }
    #pragma unroll
    for (int o = 32; o > 0; o >>= 1) s += __shfl_down(s, o, 64);
    __shared__ float red[4];
    if ((threadIdx.x & 63) == 0) red[threadIdx.x >> 6] = s;
    __syncthreads();
    if (threadIdx.x == 0) {
        float t = red[0] + red[1] + red[2] + red[3];
        h[b * 64 + j] = fmaxf(t + fc1b[j], 0.f);
    }
}

// ---------------- FC2 + sigmoid ----------------
__global__ __launch_bounds__(64) void fc2_kernel(
        const float* __restrict__ h, const float* __restrict__ fc2w,
        const float* __restrict__ fc2b, float* __restrict__ outp) {
    int b = blockIdx.x;
    float v = h[b * 64 + threadIdx.x] * fc2w[threadIdx.x];
    #pragma unroll
    for (int o = 32; o > 0; o >>= 1) v += __shfl_down(v, o, 64);
    if (threadIdx.x == 0) outp[b] = 1.f / (1.f + expf(-(v + fc2b[0])));
}

// ---------------- Launch ----------------
extern "C" void kernel_launch(void* const* d_in, const int* in_sizes, int n_in,
                              void* d_out, int out_size, void* d_ws, size_t ws_size,
                              hipStream_t stream) {
    const float* x       = (const float*)d_in[0];
    const float* conv1_w = (const float*)d_in[1];
    const float* conv1_b = (const float*)d_in[2];
    const float* bn1_g   = (const float*)d_in[3];
    const float* bn1_b   = (const float*)d_in[4];
    const float* conv2_w = (const float*)d_in[5];
    const float* conv2_b = (const float*)d_in[6];
    const float* bn2_g   = (const float*)d_in[7];
    const float* bn2_b   = (const float*)d_in[8];
    const float* conv3_w = (const float*)d_in[9];
    const float* conv3_b = (const float*)d_in[10];
    const float* bn3_g   = (const float*)d_in[11];
    const float* bn3_b   = (const float*)d_in[12];
    const float* fc1_w   = (const float*)d_in[13];
    const float* fc1_b   = (const float*)d_in[14];
    const float* fc2_w   = (const float*)d_in[15];
    const float* fc2_b   = (const float*)d_in[16];
    float* out = (float*)d_out;

    char* wsc = (char*)d_ws;
    size_t o = 0;
    auto alloc = [&](size_t bytes) { char* p = wsc + o; o += (bytes + 255) & ~(size_t)255; return p; };
    unsigned short* laybf  = (unsigned short*)alloc((size_t)BB * 64 * 64 * 64 * 2);
    unsigned short* act1bf = (unsigned short*)alloc((size_t)BB * 31 * 32 * 64 * 2);
    unsigned short* act2bf = (unsigned short*)alloc((size_t)BB * 15 * 16 * 128 * 2);
    unsigned short* wp1    = (unsigned short*)alloc((size_t)64 * 576 * 2);
    unsigned short* wp2    = (unsigned short*)alloc((size_t)128 * 576 * 2);
    unsigned short* wp3    = (unsigned short*)alloc((size_t)128 * 1152 * 2);
    float* out1   = (float*)alloc((size_t)BB * 64 * 961 * 4);
    float* out2   = (float*)alloc((size_t)BB * 128 * 225 * 4);
    float* out3   = (float*)alloc((size_t)BB * 128 * 49 * 4);
    float* act3   = (float*)alloc((size_t)BB * 128 * 49 * 4);
    float* scale1 = (float*)alloc(64 * 4);
    float* shift1 = (float*)alloc(64 * 4);
    float* scale2 = (float*)alloc(128 * 4);
    float* shift2 = (float*)alloc(128 * 4);
    float* scale3 = (float*)alloc(128 * 4);
    float* shift3 = (float*)alloc(128 * 4);
    float* hbuf   = (float*)alloc((size_t)BB * 64 * 4);

    // prepack weights + render
    wpack_kernel<<<(64 * 576 + 255) / 256, 256, 0, stream>>>(conv1_w, wp1, 64, 64);
    wpack_kernel<<<(128 * 576 + 255) / 256, 256, 0, stream>>>(conv2_w, wp2, 128, 64);
    wpack_kernel<<<(128 * 1152 + 255) / 256, 256, 0, stream>>>(conv3_w, wp3, 128, 128);
    render_nhwc_kernel<<<BB * 64, 64, 0, stream>>>(x, laybf);

    // conv1: 63->31. src [64][64][64], OCP=32, RG=RGP=2, MGN=1. grid 32*16
    gemmconv_kernel<64, 64, 64, 64, 31, 32, 2, 2, 1>
        <<<32 * 16, 256, 0, stream>>>(laybf, wp1, conv1_b, out1);
    stats_raw_kernel<<<64, 256, 0, stream>>>(out1, bn1_g, bn1_b, scale1, shift1,
                                             64, 961, (float)(BB * 961));
    applyT_kernel<64, 31, 32><<<BB * 31, 256, 0, stream>>>(out1, scale1, shift1, act1bf);

    // conv2: 31->15. src [31][32][64], OCP=16, RG=RGP=2, MGN=2. grid 32*16
    gemmconv_kernel<64, 128, 31, 32, 15, 16, 2, 2, 2>
        <<<32 * 16, 256, 0, stream>>>(act1bf, wp2, conv2_b, out2);
    stats_raw_kernel<<<128, 256, 0, stream>>>(out2, bn2_g, bn2_b, scale2, shift2,
                                              128, 225, (float)(BB * 225));
    applyT_kernel<128, 15, 16><<<BB * 15, 256, 0, stream>>>(out2, scale2, shift2, act2bf);

    // conv3: 15->7. src [15][16][128], OCP=8, RG=7, RGP=8, MGN=2. grid 32*2
    gemmconv_kernel<128, 128, 15, 16, 7, 8, 7, 8, 2>
        <<<32 * 2, 256, 0, stream>>>(act2bf, wp3, conv3_b, out3);
    stats_raw_kernel<<<128, 256, 0, stream>>>(out3, bn3_g, bn3_b, scale3, shift3,
                                              128, 49, (float)(BB * 49));
    apply_kernel<<<BB * 128, 64, 0, stream>>>(out3, scale3, shift3, act3, 128, 49);

    // FC head
    fc1_kernel<<<64 * 32, 256, 0, stream>>>(act3, fc1_w, fc1_b, hbuf);
    fc2_kernel<<<BB, 64, 0, stream>>>(hbuf, fc2_w, fc2_b, out);
}

// Round 12
// 117.141 us; speedup vs baseline: 2.3240x; 1.3266x over previous
//
#include <hip/hip_runtime.h>
#include <math.h>

#define BB 32
#define NREC 64
#define CC 16
#define HW 63

typedef __attribute__((ext_vector_type(8))) short bf16x8;
typedef __attribute__((ext_vector_type(4))) short bf16x4;
typedef __attribute__((ext_vector_type(4))) float f32x4;

__device__ __forceinline__ unsigned short f2b(float x) {
    unsigned u = __float_as_uint(x);
    u += 0x7fffu + ((u >> 16) & 1u);     // RNE; inputs finite
    return (unsigned short)(u >> 16);
}

// ---------------- Rectangle render -> NHWC bf16 [b][64u][64v][64n] ----------
__global__ __launch_bounds__(64) void render_nhwc_kernel(const float* __restrict__ x,
                                                         unsigned short* __restrict__ lay) {
    int b = blockIdx.x >> 6;
    int u = blockIdx.x & 63;
    int n = threadIdx.x;
    const float* xp = x + ((size_t)b * 64 + n) * 20;
    int xL = (int)xp[0], yT = (int)xp[1], xR = (int)xp[2], yB = (int)xp[3];
    float m = xp[4];
    #pragma unroll
    for (int c = 1; c < CC; ++c) m = fmaxf(m, xp[4 + c]);
    unsigned short mu = f2b(m);
    unsigned short* op = lay + (((size_t)b * 64 + u) * 64) * 64 + n;
    for (int v = 0; v < 64; ++v) {
        bool vb = (u < HW) && (v < HW) &&
                  (((u == xL || u == xR) && (v > yT && v < yB)) ||
                   ((v == yT || v == yB) && (u > xL && u < xR)));
        op[(size_t)v * 64] = vb ? mu : (unsigned short)0;
    }
}

// ---------------- Weight prepack: [CO][CI][3][3] f32 -> [CO][K] bf16 --------
__global__ __launch_bounds__(256) void wpack_kernel(const float* __restrict__ w,
                                                    unsigned short* __restrict__ wp,
                                                    int COUT, int CIN) {
    int K = CIN * 9;
    int idx = blockIdx.x * 256 + threadIdx.x;
    if (idx >= COUT * K) return;
    int co = idx / K, k = idx - co * K;
    int r = k / CIN, ci = k - r * CIN;
    wp[idx] = f2b(w[((size_t)co * CIN + ci) * 9 + r]);
}

// ---------------- MFMA implicit-GEMM conv 3x3 stride-2 VALID ----------------
template<int CIN, int COUT, int SR, int SC, int HOUT, int OCP, int RG, int RGP, int MGN>
__global__ __launch_bounds__(256) void gemmconv_kernel(
        const unsigned short* __restrict__ src,
        const unsigned short* __restrict__ wp,
        const float* __restrict__ bias,
        float* __restrict__ out) {
    constexpr int K   = 9 * CIN;
    constexpr int NTB = RGP * OCP / 16;
    constexpr int STR = 2 * RGP + 1;
    constexpr int STC = 2 * OCP + 1;
    constexpr int CIP = 36;
    constexpr int MTB = COUT / 16 / MGN;
    constexpr int NRG = (HOUT + RG - 1) / RG;

    __shared__ unsigned short stage[STR * STC * CIP];

    int tid = threadIdx.x;
    int wv = tid >> 6, lane = tid & 63;
    int l15 = lane & 15, lg = lane >> 4;
    int bid = blockIdx.x;
    int b  = bid & 31;
    int t2 = bid >> 5;
    int rg = t2 % NRG;
    int mg = t2 / NRG;
    int co0 = mg * (COUT / MGN);
    int mw = wv % MTB;

    f32x4 acc[NTB];
    #pragma unroll
    for (int i = 0; i < NTB; ++i) acc[i] = (f32x4){0.f, 0.f, 0.f, 0.f};

    const unsigned short* srcb = src + (size_t)b * SR * SC * CIN;
    int srow0 = 2 * rg * RG;

    for (int cb = 0; cb < CIN / 32; ++cb) {
        __syncthreads();
        for (int idx = tid; idx < STR * STC * 16; idx += 256) {
            int ci2 = idx & 15;
            int rc  = idx >> 4;
            int row = rc / STC, col = rc - row * STC;
            int srow = srow0 + row;
            unsigned v = 0;
            if (srow < SR && col < SC)
                v = *(const unsigned*)(srcb + ((size_t)srow * SC + col) * CIN + cb * 32 + ci2 * 2);
            *(unsigned*)(stage + (row * STC + col) * CIP + ci2 * 2) = v;
        }
        __syncthreads();
        #pragma unroll
        for (int r = 0; r < 9; ++r) {
            int ky = r / 3, kx = r % 3;
            int kk = r * CIN + cb * 32 + lg * 8;
            bf16x8 af = *(const bf16x8*)(wp + (size_t)(co0 + mw * 16 + l15) * K + kk);
            #pragma unroll
            for (int nt = 0; nt < NTB; ++nt) {
                int n = nt * 16 + l15;
                int dy = n / OCP, oxx = n % OCP;
                const unsigned short* sp =
                    stage + ((2 * dy + ky) * STC + (2 * oxx + kx)) * CIP + lg * 8;
                bf16x4 blo = *(const bf16x4*)sp;
                bf16x4 bhi = *(const bf16x4*)(sp + 4);
                bf16x8 bfr;
                bfr[0] = blo[0]; bfr[1] = blo[1]; bfr[2] = blo[2]; bfr[3] = blo[3];
                bfr[4] = bhi[0]; bfr[5] = bhi[1]; bfr[6] = bhi[2]; bfr[7] = bhi[3];
                acc[nt] = __builtin_amdgcn_mfma_f32_16x16x32_bf16(af, bfr, acc[nt], 0, 0, 0);
            }
        }
    }

    #pragma unroll
    for (int nt = 0; nt < NTB; ++nt) {
        int n = nt * 16 + l15;
        int oy = rg * RG + n / OCP, oxx = n % OCP;
        if (oy < HOUT && oxx < HOUT) {
            #pragma unroll
            for (int q = 0; q < 4; ++q) {
                int co = co0 + mw * 16 + lg * 4 + q;
                out[((size_t)b * COUT + co) * (HOUT * HOUT) + oy * HOUT + oxx] =
                    acc[nt][q] + bias[co];
            }
        }
    }
}

// ---------------- BN stats stage 1: one block per (c, b) plane ----------------
__global__ __launch_bounds__(256) void stats_part_kernel(
        const float* __restrict__ raw, float* __restrict__ psum,
        float* __restrict__ psq, int C, int HW2) {
    int c = blockIdx.x / BB;
    int b = blockIdx.x % BB;
    const float* rp = raw + ((size_t)b * C + c) * HW2;
    float s = 0.f, q = 0.f;
    for (int i = threadIdx.x; i < HW2; i += 256) {
        float v = rp[i];
        s += v; q += v * v;
    }
    __shared__ float rs[4], rq[4];
    int lane = threadIdx.x & 63, wv = threadIdx.x >> 6;
    #pragma unroll
    for (int o = 32; o > 0; o >>= 1) { s += __shfl_down(s, o, 64); q += __shfl_down(q, o, 64); }
    if (lane == 0) { rs[wv] = s; rq[wv] = q; }
    __syncthreads();
    if (threadIdx.x == 0) {
        psum[blockIdx.x] = rs[0] + rs[1] + rs[2] + rs[3];
        psq [blockIdx.x] = rq[0] + rq[1] + rq[2] + rq[3];
    }
}

// ---------------- BN stats stage 2: fold partials -> scale/shift ------------
__global__ void stats_fold_kernel(const float* __restrict__ psum,
                                  const float* __restrict__ psq,
                                  const float* __restrict__ g,
                                  const float* __restrict__ be,
                                  float* __restrict__ scale,
                                  float* __restrict__ shift,
                                  int C, float count) {
    int c = threadIdx.x + blockIdx.x * blockDim.x;
    if (c >= C) return;
    float S = 0.f, Q = 0.f;
    for (int b = 0; b < BB; ++b) { S += psum[c * BB + b]; Q += psq[c * BB + b]; }
    float mean = S / count;
    float var  = Q / count - mean * mean;
    float sc   = g[c] * rsqrtf(var + 1e-5f);
    scale[c] = sc;
    shift[c] = be[c] - mean * sc;
}

// ---------------- BN+ReLU + transpose to NHWC bf16 (col-padded) -------------
template<int C, int R, int SCo>
__global__ __launch_bounds__(256) void applyT_kernel(
        const float* __restrict__ raw, const float* __restrict__ scale,
        const float* __restrict__ shift, unsigned short* __restrict__ act) {
    int b = blockIdx.x / R, row = blockIdx.x % R;
    __shared__ float lds[C * (R + 2)];
    for (int idx = threadIdx.x; idx < C * R; idx += 256) {
        int ci = idx / R, col = idx - ci * R;
        float v = fmaxf(fmaf(raw[((size_t)b * C + ci) * (R * R) + row * R + col],
                             scale[ci], shift[ci]), 0.f);
        lds[ci * (R + 2) + col] = v;
    }
    __syncthreads();
    for (int idx = threadIdx.x; idx < SCo * C; idx += 256) {
        int col = idx / C, ci = idx - col * C;
        unsigned short v = 0;
        if (col < R) v = f2b(lds[ci * (R + 2) + col]);
        act[(((size_t)b * R + row) * SCo + col) * C + ci] = v;
    }
}

// ---------------- BN+ReLU packed f32 (act3 for FC) ----------------
__global__ __launch_bounds__(64) void apply_kernel(
        const float* __restrict__ raw, const float* __restrict__ scale,
        const float* __restrict__ shift, float* __restrict__ act,
        int C, int HW2) {
    int bc = blockIdx.x;
    int c = bc % C;
    const float* rp = raw + (size_t)bc * HW2;
    float* ap = act + (size_t)bc * HW2;
    float s = scale[c], h = shift[c];
    for (int i = threadIdx.x; i < HW2; i += 64)
        ap[i] = fmaxf(fmaf(rp[i], s, h), 0.f);
}

// ---------------- FC1: one block per (j, b), float4 ----------------
__global__ __launch_bounds__(256) void fc1_kernel(
        const float* __restrict__ act3, const float* __restrict__ fc1w,
        const float* __restrict__ fc1b, float* __restrict__ h) {
    const int FLAT4 = 6272 / 4;
    int j = blockIdx.x >> 5;
    int b = blockIdx.x & 31;
    const float4* ip = (const float4*)(act3 + (size_t)b * 6272);
    const float4* wp = (const float4*)(fc1w + (size_t)j * 6272);
    float s = 0.f;
    for (int i = threadIdx.x; i < FLAT4; i += 256) {
        float4 xv = ip[i], wv = wp[i];
        s = fmaf(xv.x, wv.x, s); s = fmaf(xv.y, wv.y, s);
        s = fmaf(xv.z, wv.z, s); s = fmaf(xv.w, wv.w, s);
    }
    #pragma unroll
    for (int o = 32; o > 0; o >>= 1) s += __shfl_down(s, o, 64);
    __shared__ float red[4];
    if ((threadIdx.x & 63) == 0) red[threadIdx.x >> 6] = s;
    __syncthreads();
    if (threadIdx.x == 0) {
        float t = red[0] + red[1] + red[2] + red[3];
        h[b * 64 + j] = fmaxf(t + fc1b[j], 0.f);
    }
}

// ---------------- FC2 + sigmoid ----------------
__global__ __launch_bounds__(64) void fc2_kernel(
        const float* __restrict__ h, const float* __restrict__ fc2w,
        const float* __restrict__ fc2b, float* __restrict__ outp) {
    int b = blockIdx.x;
    float v = h[b * 64 + threadIdx.x] * fc2w[threadIdx.x];
    #pragma unroll
    for (int o = 32; o > 0; o >>= 1) v += __shfl_down(v, o, 64);
    if (threadIdx.x == 0) outp[b] = 1.f / (1.f + expf(-(v + fc2b[0])));
}

// ---------------- Launch ----------------
extern "C" void kernel_launch(void* const* d_in, const int* in_sizes, int n_in,
                              void* d_out, int out_size, void* d_ws, size_t ws_size,
                              hipStream_t stream) {
    const float* x       = (const float*)d_in[0];
    const float* conv1_w = (const float*)d_in[1];
    const float* conv1_b = (const float*)d_in[2];
    const float* bn1_g   = (const float*)d_in[3];
    const float* bn1_b   = (const float*)d_in[4];
    const float* conv2_w = (const float*)d_in[5];
    const float* conv2_b = (const float*)d_in[6];
    const float* bn2_g   = (const float*)d_in[7];
    const float* bn2_b   = (const float*)d_in[8];
    const float* conv3_w = (const float*)d_in[9];
    const float* conv3_b = (const float*)d_in[10];
    const float* bn3_g   = (const float*)d_in[11];
    const float* bn3_b   = (const float*)d_in[12];
    const float* fc1_w   = (const float*)d_in[13];
    const float* fc1_b   = (const float*)d_in[14];
    const float* fc2_w   = (const float*)d_in[15];
    const float* fc2_b   = (const float*)d_in[16];
    float* out = (float*)d_out;

    char* wsc = (char*)d_ws;
    size_t o = 0;
    auto alloc = [&](size_t bytes) { char* p = wsc + o; o += (bytes + 255) & ~(size_t)255; return p; };
    unsigned short* laybf  = (unsigned short*)alloc((size_t)BB * 64 * 64 * 64 * 2);
    unsigned short* act1bf = (unsigned short*)alloc((size_t)BB * 31 * 32 * 64 * 2);
    unsigned short* act2bf = (unsigned short*)alloc((size_t)BB * 15 * 16 * 128 * 2);
    unsigned short* wp1    = (unsigned short*)alloc((size_t)64 * 576 * 2);
    unsigned short* wp2    = (unsigned short*)alloc((size_t)128 * 576 * 2);
    unsigned short* wp3    = (unsigned short*)alloc((size_t)128 * 1152 * 2);
    float* out1   = (float*)alloc((size_t)BB * 64 * 961 * 4);
    float* out2   = (float*)alloc((size_t)BB * 128 * 225 * 4);
    float* out3   = (float*)alloc((size_t)BB * 128 * 49 * 4);
    float* act3   = (float*)alloc((size_t)BB * 128 * 49 * 4);
    float* psum   = (float*)alloc((size_t)128 * BB * 4);
    float* psq    = (float*)alloc((size_t)128 * BB * 4);
    float* scale1 = (float*)alloc(64 * 4);
    float* shift1 = (float*)alloc(64 * 4);
    float* scale2 = (float*)alloc(128 * 4);
    float* shift2 = (float*)alloc(128 * 4);
    float* scale3 = (float*)alloc(128 * 4);
    float* shift3 = (float*)alloc(128 * 4);
    float* hbuf   = (float*)alloc((size_t)BB * 64 * 4);

    // prepack weights + render
    wpack_kernel<<<(64 * 576 + 255) / 256, 256, 0, stream>>>(conv1_w, wp1, 64, 64);
    wpack_kernel<<<(128 * 576 + 255) / 256, 256, 0, stream>>>(conv2_w, wp2, 128, 64);
    wpack_kernel<<<(128 * 1152 + 255) / 256, 256, 0, stream>>>(conv3_w, wp3, 128, 128);
    render_nhwc_kernel<<<BB * 64, 64, 0, stream>>>(x, laybf);

    // conv1: 63->31. grid 32*16
    gemmconv_kernel<64, 64, 64, 64, 31, 32, 2, 2, 1>
        <<<32 * 16, 256, 0, stream>>>(laybf, wp1, conv1_b, out1);
    stats_part_kernel<<<64 * BB, 256, 0, stream>>>(out1, psum, psq, 64, 961);
    stats_fold_kernel<<<1, 64, 0, stream>>>(psum, psq, bn1_g, bn1_b, scale1, shift1,
                                            64, (float)(BB * 961));
    applyT_kernel<64, 31, 32><<<BB * 31, 256, 0, stream>>>(out1, scale1, shift1, act1bf);

    // conv2: 31->15. grid 32*16
    gemmconv_kernel<64, 128, 31, 32, 15, 16, 2, 2, 2>
        <<<32 * 16, 256, 0, stream>>>(act1bf, wp2, conv2_b, out2);
    stats_part_kernel<<<128 * BB, 256, 0, stream>>>(out2, psum, psq, 128, 225);
    stats_fold_kernel<<<1, 128, 0, stream>>>(psum, psq, bn2_g, bn2_b, scale2, shift2,
                                             128, (float)(BB * 225));
    applyT_kernel<128, 15, 16><<<BB * 15, 256, 0, stream>>>(out2, scale2, shift2, act2bf);

    // conv3: 15->7. grid 32*2
    gemmconv_kernel<128, 128, 15, 16, 7, 8, 7, 8, 2>
        <<<32 * 2, 256, 0, stream>>>(act2bf, wp3, conv3_b, out3);
    stats_part_kernel<<<128 * BB, 256, 0, stream>>>(out3, psum, psq, 128, 49);
    stats_fold_kernel<<<1, 128, 0, stream>>>(psum, psq, bn3_g, bn3_b, scale3, shift3,
                                             128, (float)(BB * 49));
    apply_kernel<<<BB * 128, 64, 0, stream>>>(out3, scale3, shift3, act3, 128, 49);

    // FC head
    fc1_kernel<<<64 * 32, 256, 0, stream>>>(act3, fc1_w, fc1_b, hbuf);
    fc2_kernel<<<BB, 64, 0, stream>>>(hbuf, fc2_w, fc2_b, out);
}